// Round 1
// baseline (324.435 us; speedup 1.0000x reference)
//
#include <hip/hip_runtime.h>

typedef __attribute__((ext_vector_type(8))) short bf16x8;
typedef __attribute__((ext_vector_type(4))) float f32x4;

#define SCALE_F 0.17677669529663687f
#define LOG2E_F 1.4426950408889634f

__device__ __forceinline__ unsigned short f2bf(float f) {
    union { float f; unsigned int u; } v; v.f = f;
    unsigned int r = v.u + 0x7FFFu + ((v.u >> 16) & 1u);
    return (unsigned short)(r >> 16);
}

// XOR-swizzled byte offsets (bank-conflict fix for row-strided bf16 tiles)
__device__ __forceinline__ int swzA(int row, int col) {   // 512-B row stride: [64][256] bf16
    return ((row << 9) + (col << 1)) ^ ((row & 7) << 4);
}
__device__ __forceinline__ int swzB(int row, int col) {   // 128-B row stride: [.][64] bf16
    return ((row << 7) + (col << 1)) ^ ((row & 7) << 4);
}

// ---------------- prep kernels ----------------
extern "C" __global__ void prep_gbs_k(const float* __restrict__ emb,
                                      const float* __restrict__ pw,
                                      float* __restrict__ gbs) {
    int i = blockIdx.x * 256 + threadIdx.x;      // 8*768
    if (i >= 8 * 768) return;
    int b = i / 768, o = i - b * 768;
    const float* e = emb + b * 512;
    const float* wr = pw + o * 512;
    float s = 0.f;
    for (int k = 0; k < 512; k += 4) {
        float4 ev = *(const float4*)(e + k);
        float4 wv = *(const float4*)(wr + k);
        s += ev.x * wv.x + ev.y * wv.y + ev.z * wv.z + ev.w * wv.w;
    }
    gbs[i] = s;
}

extern "C" __global__ void prep_w_k(const float* __restrict__ wq, const float* __restrict__ wk,
                                    const float* __restrict__ wv, const float* __restrict__ wo,
                                    unsigned short* __restrict__ dst) {
    int i = blockIdx.x * 256 + threadIdx.x;      // 65536 float4-quads total
    int sel = i >> 14;
    const float* s = (sel == 0) ? wq : (sel == 1) ? wk : (sel == 2) ? wv : wo;
    float4 v = *(const float4*)(s + (i & 16383) * 4);
    ushort4 p;
    p.x = f2bf(v.x); p.y = f2bf(v.y); p.z = f2bf(v.z); p.w = f2bf(v.w);
    *(ushort4*)(dst + i * 4) = p;
}

extern "C" __global__ void prep_bias_k(const float* __restrict__ bt, float* __restrict__ bp) {
    int i = blockIdx.x * 256 + threadIdx.x;      // 8*64*64
    int h = i >> 12, r = (i >> 6) & 63, c = i & 63;
    float v;
    if (c >= 49) v = -1e30f;                     // mask pad key columns
    else if (r >= 49) v = 0.f;                   // dead query rows: any finite value
    else {
        int ri = r / 7, ci = r - ri * 7, rj = c / 7, cj = c - rj * 7;
        int rel = (ri - rj + 6) * 13 + (ci - cj + 6);
        v = bt[rel * 8 + h];
    }
    bp[i] = v;
}

// ---------------- main fused kernel ----------------
// grid 2048 (one block per window), 256 threads (4 waves). 128 KiB LDS:
//   [0,32K)   xm bf16 [64][256]   -> reused as per-wave P [64][64] slices
//   [32,64K)  q  bf16 [64][256]
//   [64,96K)  k  bf16 [64][256]   -> reused as attention-out [64][256]
//   [96,128K) v^T bf16 [256][64]
extern "C" __global__ void __launch_bounds__(256, 1)
attn_main(const float* __restrict__ x,
          const float* __restrict__ lnw, const float* __restrict__ lnb,
          const unsigned short* __restrict__ wqb, const unsigned short* __restrict__ wkb,
          const unsigned short* __restrict__ wvb, const unsigned short* __restrict__ wob,
          const float* __restrict__ gbs, const float* __restrict__ bpad,
          float* __restrict__ out)
{
    __shared__ char lds[131072];
    const int tid = threadIdx.x;
    const int w = tid >> 6;          // wave 0..3
    const int l = tid & 63;          // lane
    const int g = l >> 4;            // lane group 0..3
    const int c = l & 15;            // lane within group
    const int win = blockIdx.x;      // window 0..2047
    const int bb = win >> 8;         // batch (256 windows per batch)
    const int LQ = 32768, LK = 65536, LV = 98304;

    // ---- AdaLayerNorm -> xm (bf16, LDS) ----
    {
        float4 lnw4 = *(const float4*)(lnw + 4 * l);
        float4 lnb4 = *(const float4*)(lnb + 4 * l);
        float4 gam4 = *(const float4*)(gbs + bb * 768 + 4 * l);
        float4 bet4 = *(const float4*)(gbs + bb * 768 + 256 + 4 * l);
        for (int t = w; t < 49; t += 4) {
            float4 v = *(const float4*)(x + ((size_t)win * 49 + t) * 256 + 4 * l);
            float s = v.x + v.y + v.z + v.w;
            float ss = v.x * v.x + v.y * v.y + v.z * v.z + v.w * v.w;
            #pragma unroll
            for (int off = 32; off >= 1; off >>= 1) {
                s += __shfl_xor(s, off);
                ss += __shfl_xor(ss, off);
            }
            float mu = s * (1.0f / 256.0f);
            float var = ss * (1.0f / 256.0f) - mu * mu;
            float rstd = rsqrtf(var + 1e-5f);
            ushort4 p;
            p.x = f2bf(((v.x - mu) * rstd * lnw4.x + lnb4.x) * (1.0f + gam4.x) + bet4.x);
            p.y = f2bf(((v.y - mu) * rstd * lnw4.y + lnb4.y) * (1.0f + gam4.y) + bet4.y);
            p.z = f2bf(((v.z - mu) * rstd * lnw4.z + lnb4.z) * (1.0f + gam4.z) + bet4.z);
            p.w = f2bf(((v.w - mu) * rstd * lnw4.w + lnb4.w) * (1.0f + gam4.w) + bet4.w);
            *(ushort4*)(lds + swzA(t, 4 * l)) = p;
        }
        ushort4 z; z.x = 0; z.y = 0; z.z = 0; z.w = 0;
        for (int idx = tid; idx < 15 * 64; idx += 256) {      // zero pad rows 49..63
            int row = 49 + (idx >> 6);
            *(ushort4*)(lds + swzA(row, (idx & 63) * 4)) = z;
        }
    }
    __syncthreads();

    // ---- QKV projections ----
    // wave w owns column-tiles of heads {w, w+4}: no barrier needed before attention
    const int cmap[4] = {2 * w, 2 * w + 1, 2 * w + 8, 2 * w + 9};
    #pragma unroll
    for (int p = 0; p < 3; ++p) {
        const unsigned short* wsel = (p == 0) ? wqb : (p == 1) ? wkb : wvb;
        #pragma unroll
        for (int ci = 0; ci < 4; ++ci) {
            const int ct = cmap[ci];
            f32x4 acc0 = {0,0,0,0}, acc1 = {0,0,0,0}, acc2 = {0,0,0,0}, acc3 = {0,0,0,0};
            #pragma unroll
            for (int kt = 0; kt < 8; ++kt) {
                bf16x8 bf = *(const bf16x8*)(wsel + (ct * 16 + c) * 256 + kt * 32 + g * 8);
                bf16x8 a0 = *(const bf16x8*)(lds + swzA(c,      kt * 32 + g * 8));
                bf16x8 a1 = *(const bf16x8*)(lds + swzA(16 + c, kt * 32 + g * 8));
                bf16x8 a2 = *(const bf16x8*)(lds + swzA(32 + c, kt * 32 + g * 8));
                bf16x8 a3 = *(const bf16x8*)(lds + swzA(48 + c, kt * 32 + g * 8));
                acc0 = __builtin_amdgcn_mfma_f32_16x16x32_bf16(a0, bf, acc0, 0, 0, 0);
                acc1 = __builtin_amdgcn_mfma_f32_16x16x32_bf16(a1, bf, acc1, 0, 0, 0);
                acc2 = __builtin_amdgcn_mfma_f32_16x16x32_bf16(a2, bf, acc2, 0, 0, 0);
                acc3 = __builtin_amdgcn_mfma_f32_16x16x32_bf16(a3, bf, acc3, 0, 0, 0);
            }
            f32x4 av[4] = {acc0, acc1, acc2, acc3};
            if (p < 2) {
                const int base = (p == 0) ? LQ : LK;
                #pragma unroll
                for (int it = 0; it < 4; ++it)
                    #pragma unroll
                    for (int r = 0; r < 4; ++r)
                        *(unsigned short*)(lds + base + swzA(it * 16 + 4 * g + r, ct * 16 + c)) = f2bf(av[it][r]);
            } else {
                const int d = ct * 16 + c;          // v stored transposed: v^T[d][token]
                #pragma unroll
                for (int it = 0; it < 4; ++it) {
                    ushort4 pk;
                    pk.x = f2bf(av[it][0]); pk.y = f2bf(av[it][1]);
                    pk.z = f2bf(av[it][2]); pk.w = f2bf(av[it][3]);
                    *(ushort4*)(lds + LV + swzB(d, it * 16 + 4 * g)) = pk;
                }
            }
        }
    }
    __syncthreads();   // xm reads done -> P may reuse region

    // ---- attention: wave w handles heads w and w+4 ----
    #pragma unroll
    for (int hh = 0; hh < 2; ++hh) {
        const int h = w + 4 * hh;
        bf16x8 qf0 = *(const bf16x8*)(lds + LQ + swzA(c,      h * 32 + g * 8));
        bf16x8 qf1 = *(const bf16x8*)(lds + LQ + swzA(16 + c, h * 32 + g * 8));
        bf16x8 qf2 = *(const bf16x8*)(lds + LQ + swzA(32 + c, h * 32 + g * 8));
        bf16x8 qf3 = *(const bf16x8*)(lds + LQ + swzA(48 + c, h * 32 + g * 8));
        f32x4 sim[4][4];
        #pragma unroll
        for (int it = 0; it < 4; ++it)
            #pragma unroll
            for (int jt = 0; jt < 4; ++jt)
                sim[it][jt] = f32x4{0.f, 0.f, 0.f, 0.f};
        #pragma unroll
        for (int jt = 0; jt < 4; ++jt) {
            bf16x8 kf = *(const bf16x8*)(lds + LK + swzA(jt * 16 + c, h * 32 + g * 8));
            sim[0][jt] = __builtin_amdgcn_mfma_f32_16x16x32_bf16(qf0, kf, sim[0][jt], 0, 0, 0);
            sim[1][jt] = __builtin_amdgcn_mfma_f32_16x16x32_bf16(qf1, kf, sim[1][jt], 0, 0, 0);
            sim[2][jt] = __builtin_amdgcn_mfma_f32_16x16x32_bf16(qf2, kf, sim[2][jt], 0, 0, 0);
            sim[3][jt] = __builtin_amdgcn_mfma_f32_16x16x32_bf16(qf3, kf, sim[3][jt], 0, 0, 0);
        }
        // scale + relative-position bias (+ -1e30 mask on pad columns)
        const float* bp = bpad + h * 4096 + (4 * g) * 64 + c;
        #pragma unroll
        for (int it = 0; it < 4; ++it)
            #pragma unroll
            for (int jt = 0; jt < 4; ++jt)
                #pragma unroll
                for (int r = 0; r < 4; ++r)
                    sim[it][jt][r] = sim[it][jt][r] * SCALE_F + bp[(it * 16 + r) * 64 + jt * 16];
        // softmax over rows (i = it*16+4g+r); values spread over the 16 lanes of group g
        float inv[4][4];
        #pragma unroll
        for (int it = 0; it < 4; ++it) {
            #pragma unroll
            for (int r = 0; r < 4; ++r) {
                float m = fmaxf(fmaxf(sim[it][0][r], sim[it][1][r]), fmaxf(sim[it][2][r], sim[it][3][r]));
                m = fmaxf(m, __shfl_xor(m, 1));
                m = fmaxf(m, __shfl_xor(m, 2));
                m = fmaxf(m, __shfl_xor(m, 4));
                m = fmaxf(m, __shfl_xor(m, 8));
                float sum = 0.f;
                #pragma unroll
                for (int jt = 0; jt < 4; ++jt) {
                    float e = exp2f((sim[it][jt][r] - m) * LOG2E_F);
                    sim[it][jt][r] = e;
                    sum += e;
                }
                sum += __shfl_xor(sum, 1);
                sum += __shfl_xor(sum, 2);
                sum += __shfl_xor(sum, 4);
                sum += __shfl_xor(sum, 8);
                inv[it][r] = 1.0f / sum;
            }
        }
        // write P~ (unnormalized, <=1) to wave-private slice of xm region
        const int PB = w * 8192;
        #pragma unroll
        for (int it = 0; it < 4; ++it)
            #pragma unroll
            for (int jt = 0; jt < 4; ++jt)
                #pragma unroll
                for (int r = 0; r < 4; ++r)
                    *(unsigned short*)(lds + PB + swzB(it * 16 + 4 * g + r, jt * 16 + c)) = f2bf(sim[it][jt][r]);
        // PV: out_h[i][d] = sum_j P~[i][j] * v[j][d], then * inv[i]
        f32x4 o[4][2];
        #pragma unroll
        for (int it = 0; it < 4; ++it) { o[it][0] = f32x4{0,0,0,0}; o[it][1] = f32x4{0,0,0,0}; }
        #pragma unroll
        for (int kt = 0; kt < 2; ++kt) {
            bf16x8 pf0 = *(const bf16x8*)(lds + PB + swzB(c,      kt * 32 + g * 8));
            bf16x8 pf1 = *(const bf16x8*)(lds + PB + swzB(16 + c, kt * 32 + g * 8));
            bf16x8 pf2 = *(const bf16x8*)(lds + PB + swzB(32 + c, kt * 32 + g * 8));
            bf16x8 pf3 = *(const bf16x8*)(lds + PB + swzB(48 + c, kt * 32 + g * 8));
            #pragma unroll
            for (int dt = 0; dt < 2; ++dt) {
                bf16x8 vf = *(const bf16x8*)(lds + LV + swzB(h * 32 + dt * 16 + c, kt * 32 + g * 8));
                o[0][dt] = __builtin_amdgcn_mfma_f32_16x16x32_bf16(pf0, vf, o[0][dt], 0, 0, 0);
                o[1][dt] = __builtin_amdgcn_mfma_f32_16x16x32_bf16(pf1, vf, o[1][dt], 0, 0, 0);
                o[2][dt] = __builtin_amdgcn_mfma_f32_16x16x32_bf16(pf2, vf, o[2][dt], 0, 0, 0);
                o[3][dt] = __builtin_amdgcn_mfma_f32_16x16x32_bf16(pf3, vf, o[3][dt], 0, 0, 0);
            }
        }
        // write attention output (normalized) into k region (k cols of this head are dead)
        #pragma unroll
        for (int it = 0; it < 4; ++it)
            #pragma unroll
            for (int dt = 0; dt < 2; ++dt)
                #pragma unroll
                for (int r = 0; r < 4; ++r)
                    *(unsigned short*)(lds + LK + swzA(it * 16 + 4 * g + r, h * 32 + dt * 16 + c))
                        = f2bf(o[it][dt][r] * inv[it][r]);
    }
    __syncthreads();

    // ---- output projection + sigma gate ----
    #pragma unroll
    for (int ci = 0; ci < 4; ++ci) {
        const int ct = w * 4 + ci;
        f32x4 acc0 = {0,0,0,0}, acc1 = {0,0,0,0}, acc2 = {0,0,0,0}, acc3 = {0,0,0,0};
        #pragma unroll
        for (int kt = 0; kt < 8; ++kt) {
            bf16x8 bf = *(const bf16x8*)(wob + (ct * 16 + c) * 256 + kt * 32 + g * 8);
            bf16x8 a0 = *(const bf16x8*)(lds + LK + swzA(c,      kt * 32 + g * 8));
            bf16x8 a1 = *(const bf16x8*)(lds + LK + swzA(16 + c, kt * 32 + g * 8));
            bf16x8 a2 = *(const bf16x8*)(lds + LK + swzA(32 + c, kt * 32 + g * 8));
            bf16x8 a3 = *(const bf16x8*)(lds + LK + swzA(48 + c, kt * 32 + g * 8));
            acc0 = __builtin_amdgcn_mfma_f32_16x16x32_bf16(a0, bf, acc0, 0, 0, 0);
            acc1 = __builtin_amdgcn_mfma_f32_16x16x32_bf16(a1, bf, acc1, 0, 0, 0);
            acc2 = __builtin_amdgcn_mfma_f32_16x16x32_bf16(a2, bf, acc2, 0, 0, 0);
            acc3 = __builtin_amdgcn_mfma_f32_16x16x32_bf16(a3, bf, acc3, 0, 0, 0);
        }
        const int col = ct * 16 + c;
        const float sig = gbs[bb * 768 + 512 + col];
        f32x4 av[4] = {acc0, acc1, acc2, acc3};
        #pragma unroll
        for (int it = 0; it < 4; ++it)
            #pragma unroll
            for (int r = 0; r < 4; ++r) {
                int i = it * 16 + 4 * g + r;
                if (i < 49)
                    out[((size_t)win * 49 + i) * 256 + col] = av[it][r] * sig;
            }
    }
}

extern "C" void kernel_launch(void* const* d_in, const int* in_sizes, int n_in,
                              void* d_out, int out_size, void* d_ws, size_t ws_size,
                              hipStream_t stream) {
    (void)in_sizes; (void)n_in; (void)out_size; (void)ws_size;
    const float* x   = (const float*)d_in[0];
    const float* emb = (const float*)d_in[1];
    const float* lnw = (const float*)d_in[2];
    const float* lnb = (const float*)d_in[3];
    const float* pw  = (const float*)d_in[4];
    const float* wq  = (const float*)d_in[5];
    const float* wk  = (const float*)d_in[6];
    const float* wv  = (const float*)d_in[7];
    const float* wo  = (const float*)d_in[8];
    const float* bt  = (const float*)d_in[9];
    float* out = (float*)d_out;

    char* ws = (char*)d_ws;
    float* gbs = (float*)ws;                                   // 24576 B
    unsigned short* wb = (unsigned short*)(ws + 24576);        // 524288 B (wq,wk,wv,wo bf16)
    float* biasp = (float*)(ws + 24576 + 524288);              // 131072 B

    prep_gbs_k<<<24, 256, 0, stream>>>(emb, pw, gbs);
    prep_w_k<<<256, 256, 0, stream>>>(wq, wk, wv, wo, wb);
    prep_bias_k<<<128, 256, 0, stream>>>(bt, biasp);
    attn_main<<<2048, 256, 0, stream>>>(x, lnw, lnb,
                                        wb, wb + 65536, wb + 131072, wb + 196608,
                                        gbs, biasp, out);
}

// Round 2
// 258.654 us; speedup vs baseline: 1.2543x; 1.2543x over previous
//
#include <hip/hip_runtime.h>

typedef __attribute__((ext_vector_type(8))) short bf16x8;
typedef __attribute__((ext_vector_type(4))) float f32x4;

#define SCALE_F 0.17677669529663687f
#define LOG2E_F 1.4426950408889634f

__device__ __forceinline__ unsigned short f2bf(float f) {
    union { float f; unsigned int u; } v; v.f = f;
    unsigned int r = v.u + 0x7FFFu + ((v.u >> 16) & 1u);
    return (unsigned short)(r >> 16);
}

// Linear XOR swizzle: addr[4]^=row0, addr[5]^=row1^row2, addr[6]^=row2^row3.
// Makes scalar b16 fragment stores (4 rows x 16 cols) conflict-free AND keeps
// b128 fragment reads balanced (8 lanes per 16B-block index).
__device__ __forceinline__ int swzm(int row) {
    return ((row & 1) << 4)
         ^ ((((row >> 1) ^ (row >> 2)) & 1) << 5)
         ^ ((((row >> 2) ^ (row >> 3)) & 1) << 6);
}
__device__ __forceinline__ int swzA(int row, int col) {   // [64][256] bf16, 512-B rows
    return (((row << 9) + (col << 1)) ^ swzm(row));
}
__device__ __forceinline__ int swzB(int row, int col) {   // [.][64] bf16, 128-B rows
    return (((row << 7) + (col << 1)) ^ swzm(row));
}

// ---------------- prep kernels ----------------
extern "C" __global__ void prep_gbs_k(const float* __restrict__ emb,
                                      const float* __restrict__ pw,
                                      float* __restrict__ gbs) {
    int i = blockIdx.x * 256 + threadIdx.x;      // 8*768
    if (i >= 8 * 768) return;
    int b = i / 768, o = i - b * 768;
    const float* e = emb + b * 512;
    const float* wr = pw + o * 512;
    float s = 0.f;
    for (int k = 0; k < 512; k += 4) {
        float4 ev = *(const float4*)(e + k);
        float4 wv = *(const float4*)(wr + k);
        s += ev.x * wv.x + ev.y * wv.y + ev.z * wv.z + ev.w * wv.w;
    }
    gbs[i] = s;
}

extern "C" __global__ void prep_w_k(const float* __restrict__ wq, const float* __restrict__ wk,
                                    const float* __restrict__ wv, const float* __restrict__ wo,
                                    unsigned short* __restrict__ dst) {
    int i = blockIdx.x * 256 + threadIdx.x;      // 65536 float4-quads total
    int sel = i >> 14;
    const float* s = (sel == 0) ? wq : (sel == 1) ? wk : (sel == 2) ? wv : wo;
    float4 v = *(const float4*)(s + (i & 16383) * 4);
    ushort4 p;
    p.x = f2bf(v.x); p.y = f2bf(v.y); p.z = f2bf(v.z); p.w = f2bf(v.w);
    *(ushort4*)(dst + i * 4) = p;
}

extern "C" __global__ void prep_bias_k(const float* __restrict__ bt, float* __restrict__ bp) {
    int i = blockIdx.x * 256 + threadIdx.x;      // 8*64*64
    int h = i >> 12, r = (i >> 6) & 63, c = i & 63;
    float v;
    if (c >= 49) v = -1e30f;                     // mask pad key columns
    else if (r >= 49) v = 0.f;                   // dead query rows: any finite value
    else {
        int ri = r / 7, ci = r - ri * 7, rj = c / 7, cj = c - rj * 7;
        int rel = (ri - rj + 6) * 13 + (ci - cj + 6);
        v = bt[rel * 8 + h];
    }
    bp[i] = v;
}

// ---------------- main fused kernel ----------------
// grid 2048 (one block per window), 512 threads (8 waves, wave w = head w).
// 128 KiB LDS:
//   R0 [0,32K)   xm bf16 [64][256]   -> attn-out after bar2
//   R1 [32,64K)  q  bf16 [64][256]   -> P slices of waves 0-3 after bar2
//   R2 [64,96K)  k  bf16 [64][256]   -> P slices of waves 4-7 after bar2
//   R3 [96,128K) v^T bf16 [256][64]
extern "C" __global__ void __launch_bounds__(512, 1)
attn_main(const float* __restrict__ x,
          const float* __restrict__ lnw, const float* __restrict__ lnb,
          const unsigned short* __restrict__ wqb, const unsigned short* __restrict__ wkb,
          const unsigned short* __restrict__ wvb, const unsigned short* __restrict__ wob,
          const float* __restrict__ gbs, const float* __restrict__ bpad,
          float* __restrict__ out)
{
    __shared__ char lds[131072];
    const int tid = threadIdx.x;
    const int w = tid >> 6;          // wave == head, 0..7
    const int l = tid & 63;          // lane
    const int g = l >> 4;            // lane group 0..3
    const int c = l & 15;            // lane within group
    const int win = blockIdx.x;      // window 0..2047
    const int bb = win >> 8;         // batch
    const int LQ = 32768, LK = 65536, LV = 98304;

    // ---- AdaLayerNorm -> xm (bf16, LDS R0) ----
    {
        float4 lnw4 = *(const float4*)(lnw + 4 * l);
        float4 lnb4 = *(const float4*)(lnb + 4 * l);
        float4 gam4 = *(const float4*)(gbs + bb * 768 + 4 * l);
        float4 bet4 = *(const float4*)(gbs + bb * 768 + 256 + 4 * l);
        for (int t = w; t < 49; t += 8) {
            float4 v = *(const float4*)(x + ((size_t)win * 49 + t) * 256 + 4 * l);
            float s = v.x + v.y + v.z + v.w;
            float ss = v.x * v.x + v.y * v.y + v.z * v.z + v.w * v.w;
            #pragma unroll
            for (int off = 32; off >= 1; off >>= 1) {
                s += __shfl_xor(s, off);
                ss += __shfl_xor(ss, off);
            }
            float mu = s * (1.0f / 256.0f);
            float var = ss * (1.0f / 256.0f) - mu * mu;
            float rstd = rsqrtf(var + 1e-5f);
            ushort4 p;
            p.x = f2bf(((v.x - mu) * rstd * lnw4.x + lnb4.x) * (1.0f + gam4.x) + bet4.x);
            p.y = f2bf(((v.y - mu) * rstd * lnw4.y + lnb4.y) * (1.0f + gam4.y) + bet4.y);
            p.z = f2bf(((v.z - mu) * rstd * lnw4.z + lnb4.z) * (1.0f + gam4.z) + bet4.z);
            p.w = f2bf(((v.w - mu) * rstd * lnw4.w + lnb4.w) * (1.0f + gam4.w) + bet4.w);
            *(ushort4*)(lds + swzA(t, 4 * l)) = p;
        }
        ushort4 z; z.x = 0; z.y = 0; z.z = 0; z.w = 0;
        for (int idx = tid; idx < 15 * 64; idx += 512) {      // zero pad rows 49..63
            int row = 49 + (idx >> 6);
            *(ushort4*)(lds + swzA(row, (idx & 63) * 4)) = z;
        }
    }
    __syncthreads();     // bar1: xm ready

    // ---- QKV projections: wave w computes head w's columns (ct 2w, 2w+1) ----
    #pragma unroll
    for (int p = 0; p < 3; ++p) {
        const unsigned short* wsel = (p == 0) ? wqb : (p == 1) ? wkb : wvb;
        f32x4 acc[2][4];
        #pragma unroll
        for (int cti = 0; cti < 2; ++cti)
            #pragma unroll
            for (int it = 0; it < 4; ++it)
                acc[cti][it] = f32x4{0.f, 0.f, 0.f, 0.f};
        #pragma unroll
        for (int kt = 0; kt < 8; ++kt) {
            bf16x8 a0 = *(const bf16x8*)(lds + swzA(c,      kt * 32 + g * 8));
            bf16x8 a1 = *(const bf16x8*)(lds + swzA(16 + c, kt * 32 + g * 8));
            bf16x8 a2 = *(const bf16x8*)(lds + swzA(32 + c, kt * 32 + g * 8));
            bf16x8 a3 = *(const bf16x8*)(lds + swzA(48 + c, kt * 32 + g * 8));
            bf16x8 b0 = *(const bf16x8*)(wsel + ((2 * w)     * 16 + c) * 256 + kt * 32 + g * 8);
            bf16x8 b1 = *(const bf16x8*)(wsel + ((2 * w + 1) * 16 + c) * 256 + kt * 32 + g * 8);
            acc[0][0] = __builtin_amdgcn_mfma_f32_16x16x32_bf16(a0, b0, acc[0][0], 0, 0, 0);
            acc[0][1] = __builtin_amdgcn_mfma_f32_16x16x32_bf16(a1, b0, acc[0][1], 0, 0, 0);
            acc[0][2] = __builtin_amdgcn_mfma_f32_16x16x32_bf16(a2, b0, acc[0][2], 0, 0, 0);
            acc[0][3] = __builtin_amdgcn_mfma_f32_16x16x32_bf16(a3, b0, acc[0][3], 0, 0, 0);
            acc[1][0] = __builtin_amdgcn_mfma_f32_16x16x32_bf16(a0, b1, acc[1][0], 0, 0, 0);
            acc[1][1] = __builtin_amdgcn_mfma_f32_16x16x32_bf16(a1, b1, acc[1][1], 0, 0, 0);
            acc[1][2] = __builtin_amdgcn_mfma_f32_16x16x32_bf16(a2, b1, acc[1][2], 0, 0, 0);
            acc[1][3] = __builtin_amdgcn_mfma_f32_16x16x32_bf16(a3, b1, acc[1][3], 0, 0, 0);
        }
        if (p < 2) {
            const int base = (p == 0) ? LQ : LK;
            #pragma unroll
            for (int cti = 0; cti < 2; ++cti)
                #pragma unroll
                for (int it = 0; it < 4; ++it)
                    #pragma unroll
                    for (int r = 0; r < 4; ++r)
                        *(unsigned short*)(lds + base + swzA(it * 16 + 4 * g + r, (2 * w + cti) * 16 + c))
                            = f2bf(acc[cti][it][r]);
        } else {
            #pragma unroll
            for (int cti = 0; cti < 2; ++cti) {
                const int d = (2 * w + cti) * 16 + c;   // v^T[d][token]
                #pragma unroll
                for (int it = 0; it < 4; ++it) {
                    ushort4 pk;
                    pk.x = f2bf(acc[cti][it][0]); pk.y = f2bf(acc[cti][it][1]);
                    pk.z = f2bf(acc[cti][it][2]); pk.w = f2bf(acc[cti][it][3]);
                    *(ushort4*)(lds + LV + swzB(d, it * 16 + 4 * g)) = pk;
                }
            }
        }
    }

    // ---- QK^T + softmax for head w (wave-private: reads only its own Q/K cols) ----
    const int h = w;
    f32x4 sim[4][4];
    float inv[4][4];
    {
        bf16x8 qf0 = *(const bf16x8*)(lds + LQ + swzA(c,      h * 32 + g * 8));
        bf16x8 qf1 = *(const bf16x8*)(lds + LQ + swzA(16 + c, h * 32 + g * 8));
        bf16x8 qf2 = *(const bf16x8*)(lds + LQ + swzA(32 + c, h * 32 + g * 8));
        bf16x8 qf3 = *(const bf16x8*)(lds + LQ + swzA(48 + c, h * 32 + g * 8));
        #pragma unroll
        for (int it = 0; it < 4; ++it)
            #pragma unroll
            for (int jt = 0; jt < 4; ++jt)
                sim[it][jt] = f32x4{0.f, 0.f, 0.f, 0.f};
        #pragma unroll
        for (int jt = 0; jt < 4; ++jt) {
            bf16x8 kf = *(const bf16x8*)(lds + LK + swzA(jt * 16 + c, h * 32 + g * 8));
            sim[0][jt] = __builtin_amdgcn_mfma_f32_16x16x32_bf16(qf0, kf, sim[0][jt], 0, 0, 0);
            sim[1][jt] = __builtin_amdgcn_mfma_f32_16x16x32_bf16(qf1, kf, sim[1][jt], 0, 0, 0);
            sim[2][jt] = __builtin_amdgcn_mfma_f32_16x16x32_bf16(qf2, kf, sim[2][jt], 0, 0, 0);
            sim[3][jt] = __builtin_amdgcn_mfma_f32_16x16x32_bf16(qf3, kf, sim[3][jt], 0, 0, 0);
        }
        const float* bp = bpad + h * 4096 + (4 * g) * 64 + c;
        #pragma unroll
        for (int it = 0; it < 4; ++it)
            #pragma unroll
            for (int jt = 0; jt < 4; ++jt)
                #pragma unroll
                for (int r = 0; r < 4; ++r)
                    sim[it][jt][r] = sim[it][jt][r] * SCALE_F + bp[(it * 16 + r) * 64 + jt * 16];
        #pragma unroll
        for (int it = 0; it < 4; ++it) {
            #pragma unroll
            for (int r = 0; r < 4; ++r) {
                float m = fmaxf(fmaxf(sim[it][0][r], sim[it][1][r]), fmaxf(sim[it][2][r], sim[it][3][r]));
                m = fmaxf(m, __shfl_xor(m, 1));
                m = fmaxf(m, __shfl_xor(m, 2));
                m = fmaxf(m, __shfl_xor(m, 4));
                m = fmaxf(m, __shfl_xor(m, 8));
                float sum = 0.f;
                #pragma unroll
                for (int jt = 0; jt < 4; ++jt) {
                    float e = exp2f((sim[it][jt][r] - m) * LOG2E_F);
                    sim[it][jt][r] = e;
                    sum += e;
                }
                sum += __shfl_xor(sum, 1);
                sum += __shfl_xor(sum, 2);
                sum += __shfl_xor(sum, 4);
                sum += __shfl_xor(sum, 8);
                inv[it][r] = 1.0f / sum;
            }
        }
    }
    __syncthreads();     // bar2: Q/K/xm fully consumed everywhere

    // ---- P -> LDS (wave-private 8K slice of dead Q/K regions) ----
    const int PB = (w < 4) ? (LQ + w * 8192) : (LK + (w - 4) * 8192);
    #pragma unroll
    for (int it = 0; it < 4; ++it)
        #pragma unroll
        for (int jt = 0; jt < 4; ++jt)
            #pragma unroll
            for (int r = 0; r < 4; ++r)
                *(unsigned short*)(lds + PB + swzB(it * 16 + 4 * g + r, jt * 16 + c)) = f2bf(sim[it][jt][r]);

    // ---- PV ----
    {
        f32x4 o[4][2];
        #pragma unroll
        for (int it = 0; it < 4; ++it) { o[it][0] = f32x4{0,0,0,0}; o[it][1] = f32x4{0,0,0,0}; }
        #pragma unroll
        for (int kt = 0; kt < 2; ++kt) {
            bf16x8 pf0 = *(const bf16x8*)(lds + PB + swzB(c,      kt * 32 + g * 8));
            bf16x8 pf1 = *(const bf16x8*)(lds + PB + swzB(16 + c, kt * 32 + g * 8));
            bf16x8 pf2 = *(const bf16x8*)(lds + PB + swzB(32 + c, kt * 32 + g * 8));
            bf16x8 pf3 = *(const bf16x8*)(lds + PB + swzB(48 + c, kt * 32 + g * 8));
            #pragma unroll
            for (int dt = 0; dt < 2; ++dt) {
                bf16x8 vf = *(const bf16x8*)(lds + LV + swzB(h * 32 + dt * 16 + c, kt * 32 + g * 8));
                o[0][dt] = __builtin_amdgcn_mfma_f32_16x16x32_bf16(pf0, vf, o[0][dt], 0, 0, 0);
                o[1][dt] = __builtin_amdgcn_mfma_f32_16x16x32_bf16(pf1, vf, o[1][dt], 0, 0, 0);
                o[2][dt] = __builtin_amdgcn_mfma_f32_16x16x32_bf16(pf2, vf, o[2][dt], 0, 0, 0);
                o[3][dt] = __builtin_amdgcn_mfma_f32_16x16x32_bf16(pf3, vf, o[3][dt], 0, 0, 0);
            }
        }
        // attn-out (normalized) -> xm region (dead after bar2)
        #pragma unroll
        for (int it = 0; it < 4; ++it)
            #pragma unroll
            for (int dt = 0; dt < 2; ++dt)
                #pragma unroll
                for (int r = 0; r < 4; ++r)
                    *(unsigned short*)(lds + swzA(it * 16 + 4 * g + r, h * 32 + dt * 16 + c))
                        = f2bf(o[it][dt][r] * inv[it][r]);
    }
    __syncthreads();     // bar3: attn-out ready

    // ---- output projection + sigma gate: wave w -> cols [32w, 32w+32) ----
    {
        f32x4 acc[2][4];
        #pragma unroll
        for (int cti = 0; cti < 2; ++cti)
            #pragma unroll
            for (int it = 0; it < 4; ++it)
                acc[cti][it] = f32x4{0.f, 0.f, 0.f, 0.f};
        #pragma unroll
        for (int kt = 0; kt < 8; ++kt) {
            bf16x8 a0 = *(const bf16x8*)(lds + swzA(c,      kt * 32 + g * 8));
            bf16x8 a1 = *(const bf16x8*)(lds + swzA(16 + c, kt * 32 + g * 8));
            bf16x8 a2 = *(const bf16x8*)(lds + swzA(32 + c, kt * 32 + g * 8));
            bf16x8 a3 = *(const bf16x8*)(lds + swzA(48 + c, kt * 32 + g * 8));
            bf16x8 b0 = *(const bf16x8*)(wob + ((2 * w)     * 16 + c) * 256 + kt * 32 + g * 8);
            bf16x8 b1 = *(const bf16x8*)(wob + ((2 * w + 1) * 16 + c) * 256 + kt * 32 + g * 8);
            acc[0][0] = __builtin_amdgcn_mfma_f32_16x16x32_bf16(a0, b0, acc[0][0], 0, 0, 0);
            acc[0][1] = __builtin_amdgcn_mfma_f32_16x16x32_bf16(a1, b0, acc[0][1], 0, 0, 0);
            acc[0][2] = __builtin_amdgcn_mfma_f32_16x16x32_bf16(a2, b0, acc[0][2], 0, 0, 0);
            acc[0][3] = __builtin_amdgcn_mfma_f32_16x16x32_bf16(a3, b0, acc[0][3], 0, 0, 0);
            acc[1][0] = __builtin_amdgcn_mfma_f32_16x16x32_bf16(a0, b1, acc[1][0], 0, 0, 0);
            acc[1][1] = __builtin_amdgcn_mfma_f32_16x16x32_bf16(a1, b1, acc[1][1], 0, 0, 0);
            acc[1][2] = __builtin_amdgcn_mfma_f32_16x16x32_bf16(a2, b1, acc[1][2], 0, 0, 0);
            acc[1][3] = __builtin_amdgcn_mfma_f32_16x16x32_bf16(a3, b1, acc[1][3], 0, 0, 0);
        }
        #pragma unroll
        for (int cti = 0; cti < 2; ++cti) {
            const int col = (2 * w + cti) * 16 + c;
            const float sig = gbs[bb * 768 + 512 + col];
            #pragma unroll
            for (int it = 0; it < 4; ++it)
                #pragma unroll
                for (int r = 0; r < 4; ++r) {
                    int i = it * 16 + 4 * g + r;
                    if (i < 49)
                        out[((size_t)win * 49 + i) * 256 + col] = acc[cti][it][r] * sig;
                }
        }
    }
}

extern "C" void kernel_launch(void* const* d_in, const int* in_sizes, int n_in,
                              void* d_out, int out_size, void* d_ws, size_t ws_size,
                              hipStream_t stream) {
    (void)in_sizes; (void)n_in; (void)out_size; (void)ws_size;
    const float* x   = (const float*)d_in[0];
    const float* emb = (const float*)d_in[1];
    const float* lnw = (const float*)d_in[2];
    const float* lnb = (const float*)d_in[3];
    const float* pw  = (const float*)d_in[4];
    const float* wq  = (const float*)d_in[5];
    const float* wk  = (const float*)d_in[6];
    const float* wv  = (const float*)d_in[7];
    const float* wo  = (const float*)d_in[8];
    const float* bt  = (const float*)d_in[9];
    float* out = (float*)d_out;

    char* ws = (char*)d_ws;
    float* gbs = (float*)ws;                                   // 24576 B
    unsigned short* wb = (unsigned short*)(ws + 24576);        // 524288 B (wq,wk,wv,wo bf16)
    float* biasp = (float*)(ws + 24576 + 524288);              // 131072 B

    prep_gbs_k<<<24, 256, 0, stream>>>(emb, pw, gbs);
    prep_w_k<<<256, 256, 0, stream>>>(wq, wk, wv, wo, wb);
    prep_bias_k<<<128, 256, 0, stream>>>(bt, biasp);
    attn_main<<<2048, 512, 0, stream>>>(x, lnw, lnb,
                                        wb, wb + 65536, wb + 131072, wb + 196608,
                                        gbs, biasp, out);
}